// Round 2
// baseline (10591.797 us; speedup 1.0000x reference)
//
#include <hip/hip_runtime.h>

typedef unsigned short ushort_t;
typedef unsigned int uint_t;
typedef float f32x4 __attribute__((ext_vector_type(4)));
typedef short bf16x8 __attribute__((ext_vector_type(8)));

#define B_ 32
#define T_ 197
#define M_ 6304      // 32*197
#define M0_ 6272     // 32*196
#define DEPTH_ 12
#define NMAT_ 46
#define HBINS_ 16384

// ---------- ws layout (bytes) ----------
#define X_OFF    0ULL                      // f32 [6304,768]
#define H_OFF    19365888ULL               // bf16 [6304,768]
#define QKVB_OFF 29048832ULL               // bf16 [6304,2304]
#define O_OFF    58097664ULL               // bf16 [6304,768]
#define MID_OFF  67780608ULL               // bf16 [6304,3072]
#define WT_OFF   106512384ULL              // bf16 [<=3072*768] transposed weight
#define HIST_OFF 111230976ULL              // u32 [46*16384]  pass-1 histogram
#define H2_OFF   114245632ULL              // u32 [46*2*16384] pass-2 histograms
#define SUMS_OFF 120274944ULL              // f32 [46] (+pad)
#define SEL_OFF  120275200ULL              // u32 [46*4] bin1,below1,bin2,below2
#define PAR_OFF  120276224ULL              // f32 [46*2] thr, scale

__device__ __forceinline__ float b2f(ushort_t u) {
    return __uint_as_float(((uint_t)u) << 16);
}
__device__ __forceinline__ ushort_t f2b(float f) {
    uint_t u = __float_as_uint(f);
    u += 0x7FFFu + ((u >> 16) & 1u);   // RNE
    return (ushort_t)(u >> 16);
}
__device__ __forceinline__ float gelu_f(float v) {
    float u = 0.7978845608028654f * (v + 0.044715f * v * v * v);
    return 0.5f * v * (1.f + tanhf(u));
}

__device__ __forceinline__ void mat_info(int m, const float* Wqkv, const float* Wo,
                                         const float* W1, const float* W2,
                                         const float** W, int* N) {
    if (m < 12)      { *W = Wqkv + (size_t)m * 1769472;        *N = 1769472; }
    else if (m < 24) { *W = Wo   + (size_t)(m - 12) * 589824;  *N = 589824; }
    else if (m < 35) { *W = W1   + (size_t)(m - 24) * 2359296; *N = 2359296; }
    else             { *W = W2   + (size_t)(m - 35) * 2359296; *N = 2359296; }
}
__device__ __forceinline__ int mat_n(int m) {
    if (m < 12) return 1769472;
    if (m < 24) return 589824;
    return 2359296;
}

// ---------- pass 1: histogram |w| bits[30:17] + sum|w| ----------
__global__ __launch_bounds__(256) void hist1_kernel(const float* Wqkv, const float* Wo,
                                                    const float* W1, const float* W2,
                                                    uint_t* hist, float* sums) {
    __shared__ uint_t lh[HBINS_];
    int m = blockIdx.y;
    const float* W; int N;
    mat_info(m, Wqkv, Wo, W1, W2, &W, &N);
    for (int i = threadIdx.x; i < HBINS_; i += 256) lh[i] = 0;
    __syncthreads();
    float s = 0.f;
    int N4 = N >> 2;
    int stride = gridDim.x * 256;
    for (int i = blockIdx.x * 256 + threadIdx.x; i < N4; i += stride) {
        float4 w = ((const float4*)W)[i];
        float vs[4] = { w.x, w.y, w.z, w.w };
        #pragma unroll
        for (int q = 0; q < 4; q++) {
            uint_t ub = __float_as_uint(vs[q]) & 0x7FFFFFFFu;
            s += __uint_as_float(ub);
            uint_t bin = ub >> 17;
            if (bin > 16383u) bin = 16383u;
            atomicAdd(&lh[bin], 1u);
        }
    }
    __syncthreads();
    uint_t* gh = hist + (size_t)m * HBINS_;
    for (int i = threadIdx.x; i < HBINS_; i += 256)
        if (lh[i]) atomicAdd(&gh[i], lh[i]);
    for (int off = 32; off > 0; off >>= 1) s += __shfl_down(s, off, 64);
    if ((threadIdx.x & 63) == 0) atomicAdd(&sums[m], s);
}

// ---------- select pass-1 bins containing ranks N/2, N/2+1 (1-based) ----------
__global__ __launch_bounds__(256) void sel1_kernel(const uint_t* hist, uint_t* sel) {
    int m = blockIdx.x, t = threadIdx.x;
    const uint_t* gh = hist + (size_t)m * HBINS_;
    int N = mat_n(m);
    uint_t own = 0;
    for (int i = 0; i < 64; i++) own += gh[t * 64 + i];
    __shared__ uint_t cs[256];
    cs[t] = own; __syncthreads();
    for (int o = 1; o < 256; o <<= 1) {
        uint_t vv = (t >= o) ? cs[t - o] : 0u;
        __syncthreads();
        cs[t] += vv;
        __syncthreads();
    }
    uint_t c = cs[t] - own;
    uint_t r1 = (uint_t)(N >> 1), r2 = r1 + 1;
    for (int i = 0; i < 64; i++) {
        uint_t hv = gh[t * 64 + i];
        if (hv) {
            uint_t bin = (uint_t)(t * 64 + i);
            if (r1 > c && r1 <= c + hv) { sel[m * 4 + 0] = bin; sel[m * 4 + 1] = c; }
            if (r2 > c && r2 <= c + hv) { sel[m * 4 + 2] = bin; sel[m * 4 + 3] = c; }
            c += hv;
        }
    }
}

// ---------- pass 2: histogram bits[16:3] of elements in the selected bins ----------
__global__ __launch_bounds__(256) void hist2_kernel(const float* Wqkv, const float* Wo,
                                                    const float* W1, const float* W2,
                                                    const uint_t* sel, uint_t* h2) {
    int m = blockIdx.y;
    const float* W; int N;
    mat_info(m, Wqkv, Wo, W1, W2, &W, &N);
    uint_t b1 = sel[m * 4 + 0], b2 = sel[m * 4 + 2];
    uint_t* ha = h2 + (size_t)m * 2 * HBINS_;
    uint_t* hb = ha + HBINS_;
    int N4 = N >> 2;
    int stride = gridDim.x * 256;
    for (int i = blockIdx.x * 256 + threadIdx.x; i < N4; i += stride) {
        float4 w = ((const float4*)W)[i];
        float vs[4] = { w.x, w.y, w.z, w.w };
        #pragma unroll
        for (int q = 0; q < 4; q++) {
            uint_t ub = __float_as_uint(vs[q]) & 0x7FFFFFFFu;
            uint_t bin = ub >> 17;
            uint_t sub = (ub >> 3) & 0x3FFFu;
            if (bin == b1) atomicAdd(&ha[sub], 1u);
            if (bin == b2 && b2 != b1) atomicAdd(&hb[sub], 1u);
        }
    }
}

// ---------- final select: reconstruct order stats, thr = midpoint, scale = mean ----------
__global__ __launch_bounds__(256) void sel2_kernel(const uint_t* h2, const uint_t* sel,
                                                   const float* sums, float* par) {
    int m = blockIdx.x, t = threadIdx.x;
    int N = mat_n(m);
    uint_t b1 = sel[m * 4 + 0], below1 = sel[m * 4 + 1];
    uint_t b2 = sel[m * 4 + 2], below2 = sel[m * 4 + 3];
    const uint_t* ha = h2 + (size_t)m * 2 * HBINS_;
    const uint_t* hb = (b2 == b1) ? ha : ha + HBINS_;
    uint_t r1 = (uint_t)(N >> 1) - below1;      // 1-based rank within bin
    uint_t r2 = (uint_t)(N >> 1) + 1 - below2;
    __shared__ uint_t cs[256];
    __shared__ uint_t subs[2];
    // --- select r1 in ha ---
    uint_t own = 0;
    for (int i = 0; i < 64; i++) own += ha[t * 64 + i];
    cs[t] = own; __syncthreads();
    for (int o = 1; o < 256; o <<= 1) {
        uint_t vv = (t >= o) ? cs[t - o] : 0u;
        __syncthreads(); cs[t] += vv; __syncthreads();
    }
    uint_t c = cs[t] - own;
    for (int i = 0; i < 64; i++) {
        uint_t hv = ha[t * 64 + i];
        if (hv) {
            if (r1 > c && r1 <= c + hv) subs[0] = (uint_t)(t * 64 + i);
            c += hv;
        }
    }
    __syncthreads();
    // --- select r2 in hb ---
    own = 0;
    for (int i = 0; i < 64; i++) own += hb[t * 64 + i];
    cs[t] = own; __syncthreads();
    for (int o = 1; o < 256; o <<= 1) {
        uint_t vv = (t >= o) ? cs[t - o] : 0u;
        __syncthreads(); cs[t] += vv; __syncthreads();
    }
    c = cs[t] - own;
    for (int i = 0; i < 64; i++) {
        uint_t hv = hb[t * 64 + i];
        if (hv) {
            if (r2 > c && r2 <= c + hv) subs[1] = (uint_t)(t * 64 + i);
            c += hv;
        }
    }
    __syncthreads();
    if (t == 0) {
        float v1 = __uint_as_float((b1 << 17) | (subs[0] << 3) | 4u);
        float v2 = __uint_as_float((b2 << 17) | (subs[1] << 3) | 4u);
        par[2 * m]     = 0.5f * (v1 + v2);
        par[2 * m + 1] = sums[m] / (float)N;
    }
}

// ---------- quantize(+ternary) + transpose W[K,N](f32) -> Wt[N,K](bf16) ----------
__global__ __launch_bounds__(256) void trq_kernel(const float* W, ushort_t* Wt,
                                                  int K, int N, const float* params, int pidx) {
    __shared__ ushort_t tile[32][33];
    int n0 = blockIdx.x * 32, k0 = blockIdx.y * 32;
    int t = threadIdx.x;
    float thr = 0.f; ushort_t sq = 0;
    if (pidx >= 0) {
        thr = params[2 * pidx];
        sq  = f2b(params[2 * pidx + 1]);
    }
    int c = t & 31, r0 = t >> 5;
    for (int rr = r0; rr < 32; rr += 8) {
        float w = W[(size_t)(k0 + rr) * N + n0 + c];
        ushort_t u;
        if (pidx >= 0) {
            ushort_t sgn = (ushort_t)((__float_as_uint(w) >> 16) & 0x8000u);
            u = (fabsf(w) >= thr) ? (ushort_t)(sq | sgn) : (ushort_t)0;
        } else {
            u = f2b(w);
        }
        tile[rr][c] = u;
    }
    __syncthreads();
    int kk = t & 31, nr = t >> 5;
    for (int nn = nr; nn < 32; nn += 8)
        Wt[(size_t)(n0 + nn) * K + k0 + kk] = tile[kk][nn];
}

// ---------- patchify + patch LN -> bf16 ----------
__global__ __launch_bounds__(256) void patchify_kernel(const float* img, const float* g,
                                                       const float* b, ushort_t* A0) {
    int blk = blockIdx.x;             // b*196 + p
    int bb = blk / 196, p = blk % 196;
    int ph = p / 14, pw = p % 14;
    int t = threadIdx.x;
    float v[3];
    #pragma unroll
    for (int i = 0; i < 3; i++) {
        int d = t + i * 256;
        int c = d % 3, pix = d / 3, p2 = pix & 15, p1 = pix >> 4;
        size_t idx = (((size_t)(bb * 3 + c) * 224) + ph * 16 + p1) * 224 + pw * 16 + p2;
        v[i] = img[idx];
    }
    __shared__ float s1[256], s2[256];
    s1[t] = v[0] + v[1] + v[2];
    s2[t] = v[0] * v[0] + v[1] * v[1] + v[2] * v[2];
    __syncthreads();
    for (int o = 128; o > 0; o >>= 1) {
        if (t < o) { s1[t] += s1[t + o]; s2[t] += s2[t + o]; }
        __syncthreads();
    }
    float mu = s1[0] * (1.f / 768.f);
    float var = s2[0] * (1.f / 768.f) - mu * mu;
    float rs = rsqrtf(var + 1e-5f);
    #pragma unroll
    for (int i = 0; i < 3; i++) {
        int d = t + i * 256;
        A0[(size_t)blk * 768 + d] = f2b((v[i] - mu) * rs * g[d] + b[d]);
    }
}

// ---------- emb LN + cls + pos -> x (f32) ----------
__global__ __launch_bounds__(256) void assemble_kernel(const ushort_t* P, const float* cls,
                                                       const float* pos, const float* g,
                                                       const float* b, float* X) {
    int r = blockIdx.x;
    int bb = r / 197, tk = r % 197;
    int t = threadIdx.x;
    if (tk == 0) {
        #pragma unroll
        for (int i = 0; i < 3; i++) {
            int d = t + i * 256;
            X[(size_t)r * 768 + d] = cls[d] + pos[d];
        }
        return;
    }
    const ushort_t* pr = P + (size_t)(bb * 196 + tk - 1) * 768;
    float v[3];
    #pragma unroll
    for (int i = 0; i < 3; i++) v[i] = b2f(pr[t + i * 256]);
    __shared__ float s1[256], s2[256];
    s1[t] = v[0] + v[1] + v[2];
    s2[t] = v[0] * v[0] + v[1] * v[1] + v[2] * v[2];
    __syncthreads();
    for (int o = 128; o > 0; o >>= 1) {
        if (t < o) { s1[t] += s1[t + o]; s2[t] += s2[t + o]; }
        __syncthreads();
    }
    float mu = s1[0] * (1.f / 768.f);
    float var = s2[0] * (1.f / 768.f) - mu * mu;
    float rs = rsqrtf(var + 1e-5f);
    #pragma unroll
    for (int i = 0; i < 3; i++) {
        int d = t + i * 256;
        X[(size_t)r * 768 + d] =
            (v[i] - mu) * rs * g[d] + b[d] + pos[(size_t)tk * 768 + d];
    }
}

// ---------- LN: x(f32) -> bf16 h, or f32 (final output) ----------
__global__ __launch_bounds__(256) void ln_kernel(const float* X, ushort_t* Hb, float* Hf,
                                                 const float* g, const float* b) {
    int r = blockIdx.x, t = threadIdx.x;
    const float* xr = X + (size_t)r * 768;
    float v0 = xr[t], v1 = xr[t + 256], v2 = xr[t + 512];
    __shared__ float s1[256], s2[256];
    s1[t] = v0 + v1 + v2;
    s2[t] = v0 * v0 + v1 * v1 + v2 * v2;
    __syncthreads();
    for (int o = 128; o > 0; o >>= 1) {
        if (t < o) { s1[t] += s1[t + o]; s2[t] += s2[t + o]; }
        __syncthreads();
    }
    float mu = s1[0] * (1.f / 768.f);
    float var = s2[0] * (1.f / 768.f) - mu * mu;
    float rs = rsqrtf(var + 1e-5f);
    float o0 = (v0 - mu) * rs * g[t]       + b[t];
    float o1 = (v1 - mu) * rs * g[t + 256] + b[t + 256];
    float o2 = (v2 - mu) * rs * g[t + 512] + b[t + 512];
    if (Hf) {
        Hf[(size_t)r * 768 + t] = o0;
        Hf[(size_t)r * 768 + t + 256] = o1;
        Hf[(size_t)r * 768 + t + 512] = o2;
    } else {
        Hb[(size_t)r * 768 + t] = f2b(o0);
        Hb[(size_t)r * 768 + t + 256] = f2b(o1);
        Hb[(size_t)r * 768 + t + 512] = f2b(o2);
    }
}

// ---------- MFMA GEMM: C[M,N] = A[M,K](bf16) @ Bt[N,K]^T(bf16) + bias(f32) ----------
// epi: 0 = bf16 out; 1 = gelu -> bf16 out; 2 = +R (f32) -> f32 out
__global__ __launch_bounds__(256) void gemm_kernel(const ushort_t* A, const ushort_t* Bt,
                                                   const float* bias, void* Cout,
                                                   const float* R, int M, int N, int K, int epi) {
    __shared__ ushort_t As[128][40];   // +8 pad
    __shared__ ushort_t Bs[128][40];
    int t = threadIdx.x;
    int lane = t & 63, wave = t >> 6;
    int row0 = blockIdx.y * 128, col0 = blockIdx.x * 128;
    int sr = t >> 1, shalf = t & 1;
    int wm = (wave >> 1) * 64, wn = (wave & 1) * 64;
    int fr = lane & 15, fq = lane >> 4;
    f32x4 acc[4][4];
    #pragma unroll
    for (int i = 0; i < 4; i++)
        #pragma unroll
        for (int j = 0; j < 4; j++)
            acc[i][j] = (f32x4){0.f, 0.f, 0.f, 0.f};

    for (int k0 = 0; k0 < K; k0 += 32) {
        #pragma unroll
        for (int j = 0; j < 2; j++) {
            int koff = (shalf + 2 * j) * 8;
            int grow = row0 + sr;
            uint4 av = make_uint4(0u, 0u, 0u, 0u);
            if (grow < M) av = *(const uint4*)(A + (size_t)grow * K + k0 + koff);
            *(uint4*)&As[sr][koff] = av;
            uint4 bv = *(const uint4*)(Bt + (size_t)(col0 + sr) * K + k0 + koff);
            *(uint4*)&Bs[sr][koff] = bv;
        }
        __syncthreads();
        bf16x8 af[4], bfr[4];
        #pragma unroll
        for (int mt = 0; mt < 4; mt++)
            af[mt] = *(const bf16x8*)&As[wm + mt * 16 + fr][fq * 8];
        #pragma unroll
        for (int nt = 0; nt < 4; nt++)
            bfr[nt] = *(const bf16x8*)&Bs[wn + nt * 16 + fr][fq * 8];
        #pragma unroll
        for (int mt = 0; mt < 4; mt++)
            #pragma unroll
            for (int nt = 0; nt < 4; nt++)
                acc[mt][nt] = __builtin_amdgcn_mfma_f32_16x16x32_bf16(
                    af[mt], bfr[nt], acc[mt][nt], 0, 0, 0);
        __syncthreads();
    }
    // D layout: col = lane&15, row = (lane>>4)*4 + reg
    #pragma unroll
    for (int nt = 0; nt < 4; nt++) {
        int col = col0 + wn + nt * 16 + fr;
        float bv = bias[col];
        #pragma unroll
        for (int mt = 0; mt < 4; mt++) {
            #pragma unroll
            for (int gi = 0; gi < 4; gi++) {
                int row = row0 + wm + mt * 16 + fq * 4 + gi;
                if (row < M) {
                    float val = acc[mt][nt][gi] + bv;
                    if (epi == 1) val = gelu_f(val);
                    size_t off = (size_t)row * N + col;
                    if (epi == 2) ((float*)Cout)[off] = val + R[off];
                    else          ((ushort_t*)Cout)[off] = f2b(val);
                }
            }
        }
    }
}

// ---------- attention: qkv(bf16) -> o(bf16). one block per (b,head) x qchunk ----------
__global__ __launch_bounds__(256) void attn_kernel(const ushort_t* qkv, ushort_t* O) {
    __shared__ ushort_t Kt[64][198];   // K^T: [d][j]
    __shared__ ushort_t Vs[197][66];   // V:   [j][d]
    __shared__ float qv[64];
    __shared__ float pv[200];
    __shared__ float rbuf[4];
    __shared__ float part[4][64];
    int bh = blockIdx.x;
    int bb = bh / 12, hh = bh % 12;
    int t = threadIdx.x, lane = t & 63, wave = t >> 6;
    size_t base = (size_t)bb * 197 * 2304;
    for (int e = t; e < 197 * 64; e += 256) {
        int j = e >> 6, d = e & 63;
        size_t rowp = base + (size_t)j * 2304 + hh * 64 + d;
        Kt[d][j] = qkv[rowp + 768];
        Vs[j][d] = qkv[rowp + 1536];
    }
    __syncthreads();
    int i0 = blockIdx.y * 50, i1 = min(197, i0 + 50);
    for (int i = i0; i < i1; i++) {
        if (t < 64) qv[t] = b2f(qkv[base + (size_t)i * 2304 + hh * 64 + t]) * 0.125f;
        __syncthreads();
        float s = -1e30f;
        if (t < 197) {
            s = 0.f;
            for (int d = 0; d < 64; d++) s += qv[d] * b2f(Kt[d][t]);
        }
        float wm = s;
        for (int off = 32; off > 0; off >>= 1) wm = fmaxf(wm, __shfl_down(wm, off, 64));
        if (lane == 0) rbuf[wave] = wm;
        __syncthreads();
        float mx = fmaxf(fmaxf(rbuf[0], rbuf[1]), fmaxf(rbuf[2], rbuf[3]));
        float p = (t < 197) ? __expf(s - mx) : 0.f;
        float wsum = p;
        for (int off = 32; off > 0; off >>= 1) wsum += __shfl_down(wsum, off, 64);
        __syncthreads();
        if (lane == 0) rbuf[wave] = wsum;
        __syncthreads();
        float tot = rbuf[0] + rbuf[1] + rbuf[2] + rbuf[3];
        if (t < 197) pv[t] = p / tot;
        __syncthreads();
        int d = t & 63, c = t >> 6;
        float acc = 0.f;
        for (int j = c; j < 197; j += 4) acc += pv[j] * b2f(Vs[j][d]);
        part[c][d] = acc;
        __syncthreads();
        if (t < 64) {
            float ov = part[0][t] + part[1][t] + part[2][t] + part[3][t];
            O[(size_t)(bb * 197 + i) * 768 + hh * 64 + t] = f2b(ov);
        }
        __syncthreads();
    }
}

extern "C" void kernel_launch(void* const* d_in, const int* in_sizes, int n_in,
                              void* d_out, int out_size, void* d_ws, size_t ws_size,
                              hipStream_t stream) {
    const float* img   = (const float*)d_in[0];
    const float* plg   = (const float*)d_in[1];
    const float* plb   = (const float*)d_in[2];
    const float* Wp    = (const float*)d_in[3];
    const float* bp    = (const float*)d_in[4];
    const float* elg   = (const float*)d_in[5];
    const float* elb   = (const float*)d_in[6];
    const float* pos   = (const float*)d_in[7];
    const float* cls   = (const float*)d_in[8];
    const float* l1g   = (const float*)d_in[9];
    const float* l1b   = (const float*)d_in[10];
    const float* Wqkv  = (const float*)d_in[11];
    const float* bqkv  = (const float*)d_in[12];
    const float* Wo    = (const float*)d_in[13];
    const float* bo    = (const float*)d_in[14];
    const float* l2g   = (const float*)d_in[15];
    const float* l2b   = (const float*)d_in[16];
    const float* W1    = (const float*)d_in[17];
    const float* b1    = (const float*)d_in[18];
    const float* W2    = (const float*)d_in[19];
    const float* b2    = (const float*)d_in[20];
    const float* ng    = (const float*)d_in[21];
    const float* nb    = (const float*)d_in[22];

    char* ws = (char*)d_ws;
    float*    x    = (float*)(ws + X_OFF);
    ushort_t* h    = (ushort_t*)(ws + H_OFF);
    ushort_t* qkvb = (ushort_t*)(ws + QKVB_OFF);
    ushort_t* o    = (ushort_t*)(ws + O_OFF);
    ushort_t* mid  = (ushort_t*)(ws + MID_OFF);
    ushort_t* wt   = (ushort_t*)(ws + WT_OFF);
    uint_t*   hist = (uint_t*)(ws + HIST_OFF);
    uint_t*   h2   = (uint_t*)(ws + H2_OFF);
    float*    sums = (float*)(ws + SUMS_OFF);
    uint_t*   sel  = (uint_t*)(ws + SEL_OFF);
    float*    par  = (float*)(ws + PAR_OFF);

    // zero hist + h2 + sums (ws re-poisoned 0xAA before every timed launch)
    hipMemsetAsync(ws + HIST_OFF, 0, SEL_OFF - HIST_OFF, stream);

    hist1_kernel<<<dim3(64, NMAT_), 256, 0, stream>>>(Wqkv, Wo, W1, W2, hist, sums);
    sel1_kernel<<<NMAT_, 256, 0, stream>>>(hist, sel);
    hist2_kernel<<<dim3(64, NMAT_), 256, 0, stream>>>(Wqkv, Wo, W1, W2, sel, h2);
    sel2_kernel<<<NMAT_, 256, 0, stream>>>(h2, sel, sums, par);

    // embedding
    patchify_kernel<<<M0_, 256, 0, stream>>>(img, plg, plb, h);
    trq_kernel<<<dim3(768 / 32, 768 / 32), 256, 0, stream>>>(Wp, wt, 768, 768, par, -1);
    gemm_kernel<<<dim3(6, 49), 256, 0, stream>>>(h, wt, bp, o, nullptr, M0_, 768, 768, 0);
    assemble_kernel<<<M_, 256, 0, stream>>>(o, cls, pos, elg, elb, x);

    for (int i = 0; i < DEPTH_; i++) {
        ln_kernel<<<M_, 256, 0, stream>>>(x, h, nullptr, l1g + i * 768, l1b + i * 768);
        trq_kernel<<<dim3(2304 / 32, 768 / 32), 256, 0, stream>>>(
            Wqkv + (size_t)i * 1769472, wt, 768, 2304, par, i);
        gemm_kernel<<<dim3(18, 50), 256, 0, stream>>>(h, wt, bqkv + i * 2304, qkvb, nullptr,
                                                      M_, 2304, 768, 0);
        attn_kernel<<<dim3(B_ * 12, 4), 256, 0, stream>>>(qkvb, o);
        trq_kernel<<<dim3(768 / 32, 768 / 32), 256, 0, stream>>>(
            Wo + (size_t)i * 589824, wt, 768, 768, par, 12 + i);
        gemm_kernel<<<dim3(6, 50), 256, 0, stream>>>(o, wt, bo + i * 768, x, x,
                                                     M_, 768, 768, 2);
        ln_kernel<<<M_, 256, 0, stream>>>(x, h, nullptr, l2g + i * 768, l2b + i * 768);
        trq_kernel<<<dim3(3072 / 32, 768 / 32), 256, 0, stream>>>(
            W1 + (size_t)i * 2359296, wt, 768, 3072, par, (i < 11) ? 24 + i : -1);
        gemm_kernel<<<dim3(24, 50), 256, 0, stream>>>(h, wt, b1 + i * 3072, mid, nullptr,
                                                      M_, 3072, 768, 1);
        trq_kernel<<<dim3(768 / 32, 3072 / 32), 256, 0, stream>>>(
            W2 + (size_t)i * 2359296, wt, 3072, 768, par, (i < 11) ? 35 + i : -1);
        gemm_kernel<<<dim3(6, 50), 256, 0, stream>>>(mid, wt, b2 + i * 768, x, x,
                                                     M_, 768, 3072, 2);
    }

    ln_kernel<<<M_, 256, 0, stream>>>(x, nullptr, (float*)d_out, ng, nb);
}

// Round 3
// 5749.150 us; speedup vs baseline: 1.8423x; 1.8423x over previous
//
#include <hip/hip_runtime.h>

typedef unsigned short ushort_t;
typedef unsigned int uint_t;
typedef float f32x4 __attribute__((ext_vector_type(4)));
typedef short bf16x8 __attribute__((ext_vector_type(8)));

#define B_ 32
#define T_ 197
#define M_ 6304      // 32*197
#define M0_ 6272     // 32*196
#define DEPTH_ 12
#define NMAT_ 46
#define HBINS_ 16384

// ---------- ws layout (bytes) ----------
#define X_OFF    0ULL                      // f32 [6304,768]
#define H_OFF    19365888ULL               // bf16 [6304,768]
#define QKVB_OFF 29048832ULL               // bf16 [6304,2304]
#define O_OFF    58097664ULL               // bf16 [6304,768]
#define MID_OFF  67780608ULL               // bf16 [6304,3072]
#define WT_OFF   106512384ULL              // bf16 [<=3072*768] transposed weight
#define HIST_OFF 111230976ULL              // u32 [46*16384]  pass-1 histogram
#define H2_OFF   114245632ULL              // u32 [46*2*16384] pass-2 histograms
#define SUMS_OFF 120274944ULL              // f32 [46] (+pad)
#define SEL_OFF  120275200ULL              // u32 [46*4] bin1,below1,bin2,below2
#define PAR_OFF  120276224ULL              // f32 [46*2] thr, scale

__device__ __forceinline__ float b2f(ushort_t u) {
    return __uint_as_float(((uint_t)u) << 16);
}
__device__ __forceinline__ ushort_t f2b(float f) {
    uint_t u = __float_as_uint(f);
    u += 0x7FFFu + ((u >> 16) & 1u);   // RNE
    return (ushort_t)(u >> 16);
}
__device__ __forceinline__ float gelu_f(float v) {
    float u = 0.7978845608028654f * (v + 0.044715f * v * v * v);
    return 0.5f * v * (1.f + tanhf(u));
}

__device__ __forceinline__ void mat_info(int m, const float* Wqkv, const float* Wo,
                                         const float* W1, const float* W2,
                                         const float** W, int* N) {
    if (m < 12)      { *W = Wqkv + (size_t)m * 1769472;        *N = 1769472; }
    else if (m < 24) { *W = Wo   + (size_t)(m - 12) * 589824;  *N = 589824; }
    else if (m < 35) { *W = W1   + (size_t)(m - 24) * 2359296; *N = 2359296; }
    else             { *W = W2   + (size_t)(m - 35) * 2359296; *N = 2359296; }
}
__device__ __forceinline__ int mat_n(int m) {
    if (m < 12) return 1769472;
    if (m < 24) return 589824;
    return 2359296;
}

// ---------- pass 1: histogram |w| bits[30:17] + sum|w| ----------
__global__ __launch_bounds__(256) void hist1_kernel(const float* Wqkv, const float* Wo,
                                                    const float* W1, const float* W2,
                                                    uint_t* hist, float* sums) {
    __shared__ uint_t lh[HBINS_];
    int m = blockIdx.y;
    const float* W; int N;
    mat_info(m, Wqkv, Wo, W1, W2, &W, &N);
    for (int i = threadIdx.x; i < HBINS_; i += 256) lh[i] = 0;
    __syncthreads();
    float s = 0.f;
    int N4 = N >> 2;
    int stride = gridDim.x * 256;
    for (int i = blockIdx.x * 256 + threadIdx.x; i < N4; i += stride) {
        float4 w = ((const float4*)W)[i];
        float vs[4] = { w.x, w.y, w.z, w.w };
        #pragma unroll
        for (int q = 0; q < 4; q++) {
            uint_t ub = __float_as_uint(vs[q]) & 0x7FFFFFFFu;
            s += __uint_as_float(ub);
            uint_t bin = ub >> 17;
            if (bin > 16383u) bin = 16383u;
            atomicAdd(&lh[bin], 1u);
        }
    }
    __syncthreads();
    uint_t* gh = hist + (size_t)m * HBINS_;
    for (int i = threadIdx.x; i < HBINS_; i += 256)
        if (lh[i]) atomicAdd(&gh[i], lh[i]);
    for (int off = 32; off > 0; off >>= 1) s += __shfl_down(s, off, 64);
    if ((threadIdx.x & 63) == 0) atomicAdd(&sums[m], s);
}

// ---------- select pass-1 bins containing ranks N/2, N/2+1 (1-based) ----------
__global__ __launch_bounds__(256) void sel1_kernel(const uint_t* hist, uint_t* sel) {
    int m = blockIdx.x, t = threadIdx.x;
    const uint_t* gh = hist + (size_t)m * HBINS_;
    int N = mat_n(m);
    uint_t own = 0;
    for (int i = 0; i < 64; i++) own += gh[t * 64 + i];
    __shared__ uint_t cs[256];
    cs[t] = own; __syncthreads();
    for (int o = 1; o < 256; o <<= 1) {
        uint_t vv = (t >= o) ? cs[t - o] : 0u;
        __syncthreads();
        cs[t] += vv;
        __syncthreads();
    }
    uint_t c = cs[t] - own;
    uint_t r1 = (uint_t)(N >> 1), r2 = r1 + 1;
    for (int i = 0; i < 64; i++) {
        uint_t hv = gh[t * 64 + i];
        if (hv) {
            uint_t bin = (uint_t)(t * 64 + i);
            if (r1 > c && r1 <= c + hv) { sel[m * 4 + 0] = bin; sel[m * 4 + 1] = c; }
            if (r2 > c && r2 <= c + hv) { sel[m * 4 + 2] = bin; sel[m * 4 + 3] = c; }
            c += hv;
        }
    }
}

// ---------- pass 2: histogram bits[16:3] of elements in the selected bins ----------
__global__ __launch_bounds__(256) void hist2_kernel(const float* Wqkv, const float* Wo,
                                                    const float* W1, const float* W2,
                                                    const uint_t* sel, uint_t* h2) {
    int m = blockIdx.y;
    const float* W; int N;
    mat_info(m, Wqkv, Wo, W1, W2, &W, &N);
    uint_t b1 = sel[m * 4 + 0], b2 = sel[m * 4 + 2];
    uint_t* ha = h2 + (size_t)m * 2 * HBINS_;
    uint_t* hb = ha + HBINS_;
    int N4 = N >> 2;
    int stride = gridDim.x * 256;
    for (int i = blockIdx.x * 256 + threadIdx.x; i < N4; i += stride) {
        float4 w = ((const float4*)W)[i];
        float vs[4] = { w.x, w.y, w.z, w.w };
        #pragma unroll
        for (int q = 0; q < 4; q++) {
            uint_t ub = __float_as_uint(vs[q]) & 0x7FFFFFFFu;
            uint_t bin = ub >> 17;
            uint_t sub = (ub >> 3) & 0x3FFFu;
            if (bin == b1) atomicAdd(&ha[sub], 1u);
            if (bin == b2 && b2 != b1) atomicAdd(&hb[sub], 1u);
        }
    }
}

// ---------- final select: reconstruct order stats, thr = midpoint, scale = mean ----------
__global__ __launch_bounds__(256) void sel2_kernel(const uint_t* h2, const uint_t* sel,
                                                   const float* sums, float* par) {
    int m = blockIdx.x, t = threadIdx.x;
    int N = mat_n(m);
    uint_t b1 = sel[m * 4 + 0], below1 = sel[m * 4 + 1];
    uint_t b2 = sel[m * 4 + 2], below2 = sel[m * 4 + 3];
    const uint_t* ha = h2 + (size_t)m * 2 * HBINS_;
    const uint_t* hb = (b2 == b1) ? ha : ha + HBINS_;
    uint_t r1 = (uint_t)(N >> 1) - below1;
    uint_t r2 = (uint_t)(N >> 1) + 1 - below2;
    __shared__ uint_t cs[256];
    __shared__ uint_t subs[2];
    uint_t own = 0;
    for (int i = 0; i < 64; i++) own += ha[t * 64 + i];
    cs[t] = own; __syncthreads();
    for (int o = 1; o < 256; o <<= 1) {
        uint_t vv = (t >= o) ? cs[t - o] : 0u;
        __syncthreads(); cs[t] += vv; __syncthreads();
    }
    uint_t c = cs[t] - own;
    for (int i = 0; i < 64; i++) {
        uint_t hv = ha[t * 64 + i];
        if (hv) {
            if (r1 > c && r1 <= c + hv) subs[0] = (uint_t)(t * 64 + i);
            c += hv;
        }
    }
    __syncthreads();
    own = 0;
    for (int i = 0; i < 64; i++) own += hb[t * 64 + i];
    cs[t] = own; __syncthreads();
    for (int o = 1; o < 256; o <<= 1) {
        uint_t vv = (t >= o) ? cs[t - o] : 0u;
        __syncthreads(); cs[t] += vv; __syncthreads();
    }
    c = cs[t] - own;
    for (int i = 0; i < 64; i++) {
        uint_t hv = hb[t * 64 + i];
        if (hv) {
            if (r2 > c && r2 <= c + hv) subs[1] = (uint_t)(t * 64 + i);
            c += hv;
        }
    }
    __syncthreads();
    if (t == 0) {
        float v1 = __uint_as_float((b1 << 17) | (subs[0] << 3) | 4u);
        float v2 = __uint_as_float((b2 << 17) | (subs[1] << 3) | 4u);
        par[2 * m]     = 0.5f * (v1 + v2);
        par[2 * m + 1] = sums[m] / (float)N;
    }
}

// ---------- quantize(+ternary) + transpose W[K,N](f32) -> Wt[N,K](bf16) ----------
__global__ __launch_bounds__(256) void trq_kernel(const float* W, ushort_t* Wt,
                                                  int K, int N, const float* params, int pidx) {
    __shared__ ushort_t tile[32][33];
    int n0 = blockIdx.x * 32, k0 = blockIdx.y * 32;
    int t = threadIdx.x;
    float thr = 0.f; ushort_t sq = 0;
    if (pidx >= 0) {
        thr = params[2 * pidx];
        sq  = f2b(params[2 * pidx + 1]);
    }
    int c = t & 31, r0 = t >> 5;
    for (int rr = r0; rr < 32; rr += 8) {
        float w = W[(size_t)(k0 + rr) * N + n0 + c];
        ushort_t u;
        if (pidx >= 0) {
            ushort_t sgn = (ushort_t)((__float_as_uint(w) >> 16) & 0x8000u);
            u = (fabsf(w) >= thr) ? (ushort_t)(sq | sgn) : (ushort_t)0;
        } else {
            u = f2b(w);
        }
        tile[rr][c] = u;
    }
    __syncthreads();
    int kk = t & 31, nr = t >> 5;
    for (int nn = nr; nn < 32; nn += 8)
        Wt[(size_t)(n0 + nn) * K + k0 + kk] = tile[kk][nn];
}

// ---------- patchify + patch LN -> bf16 ----------
__global__ __launch_bounds__(256) void patchify_kernel(const float* img, const float* g,
                                                       const float* b, ushort_t* A0) {
    int blk = blockIdx.x;
    int bb = blk / 196, p = blk % 196;
    int ph = p / 14, pw = p % 14;
    int t = threadIdx.x;
    float v[3];
    #pragma unroll
    for (int i = 0; i < 3; i++) {
        int d = t + i * 256;
        int c = d % 3, pix = d / 3, p2 = pix & 15, p1 = pix >> 4;
        size_t idx = (((size_t)(bb * 3 + c) * 224) + ph * 16 + p1) * 224 + pw * 16 + p2;
        v[i] = img[idx];
    }
    __shared__ float s1[256], s2[256];
    s1[t] = v[0] + v[1] + v[2];
    s2[t] = v[0] * v[0] + v[1] * v[1] + v[2] * v[2];
    __syncthreads();
    for (int o = 128; o > 0; o >>= 1) {
        if (t < o) { s1[t] += s1[t + o]; s2[t] += s2[t + o]; }
        __syncthreads();
    }
    float mu = s1[0] * (1.f / 768.f);
    float var = s2[0] * (1.f / 768.f) - mu * mu;
    float rs = rsqrtf(var + 1e-5f);
    #pragma unroll
    for (int i = 0; i < 3; i++) {
        int d = t + i * 256;
        A0[(size_t)blk * 768 + d] = f2b((v[i] - mu) * rs * g[d] + b[d]);
    }
}

// ---------- emb LN + cls + pos -> x (f32) ----------
__global__ __launch_bounds__(256) void assemble_kernel(const ushort_t* P, const float* cls,
                                                       const float* pos, const float* g,
                                                       const float* b, float* X) {
    int r = blockIdx.x;
    int bb = r / 197, tk = r % 197;
    int t = threadIdx.x;
    if (tk == 0) {
        #pragma unroll
        for (int i = 0; i < 3; i++) {
            int d = t + i * 256;
            X[(size_t)r * 768 + d] = cls[d] + pos[d];
        }
        return;
    }
    const ushort_t* pr = P + (size_t)(bb * 196 + tk - 1) * 768;
    float v[3];
    #pragma unroll
    for (int i = 0; i < 3; i++) v[i] = b2f(pr[t + i * 256]);
    __shared__ float s1[256], s2[256];
    s1[t] = v[0] + v[1] + v[2];
    s2[t] = v[0] * v[0] + v[1] * v[1] + v[2] * v[2];
    __syncthreads();
    for (int o = 128; o > 0; o >>= 1) {
        if (t < o) { s1[t] += s1[t + o]; s2[t] += s2[t + o]; }
        __syncthreads();
    }
    float mu = s1[0] * (1.f / 768.f);
    float var = s2[0] * (1.f / 768.f) - mu * mu;
    float rs = rsqrtf(var + 1e-5f);
    #pragma unroll
    for (int i = 0; i < 3; i++) {
        int d = t + i * 256;
        X[(size_t)r * 768 + d] =
            (v[i] - mu) * rs * g[d] + b[d] + pos[(size_t)tk * 768 + d];
    }
}

// ---------- LN: x(f32) -> bf16 h, or f32 (final output) ----------
__global__ __launch_bounds__(256) void ln_kernel(const float* X, ushort_t* Hb, float* Hf,
                                                 const float* g, const float* b) {
    int r = blockIdx.x, t = threadIdx.x;
    const float* xr = X + (size_t)r * 768;
    float v0 = xr[t], v1 = xr[t + 256], v2 = xr[t + 512];
    __shared__ float s1[256], s2[256];
    s1[t] = v0 + v1 + v2;
    s2[t] = v0 * v0 + v1 * v1 + v2 * v2;
    __syncthreads();
    for (int o = 128; o > 0; o >>= 1) {
        if (t < o) { s1[t] += s1[t + o]; s2[t] += s2[t + o]; }
        __syncthreads();
    }
    float mu = s1[0] * (1.f / 768.f);
    float var = s2[0] * (1.f / 768.f) - mu * mu;
    float rs = rsqrtf(var + 1e-5f);
    float o0 = (v0 - mu) * rs * g[t]       + b[t];
    float o1 = (v1 - mu) * rs * g[t + 256] + b[t + 256];
    float o2 = (v2 - mu) * rs * g[t + 512] + b[t + 512];
    if (Hf) {
        Hf[(size_t)r * 768 + t] = o0;
        Hf[(size_t)r * 768 + t + 256] = o1;
        Hf[(size_t)r * 768 + t + 512] = o2;
    } else {
        Hb[(size_t)r * 768 + t] = f2b(o0);
        Hb[(size_t)r * 768 + t + 256] = f2b(o1);
        Hb[(size_t)r * 768 + t + 512] = f2b(o2);
    }
}

// ---------- MFMA GEMM: C[M,N] = A[M,K](bf16) @ Bt[N,K]^T(bf16) + bias(f32) ----------
__global__ __launch_bounds__(256) void gemm_kernel(const ushort_t* A, const ushort_t* Bt,
                                                   const float* bias, void* Cout,
                                                   const float* R, int M, int N, int K, int epi) {
    __shared__ ushort_t As[128][40];
    __shared__ ushort_t Bs[128][40];
    int t = threadIdx.x;
    int lane = t & 63, wave = t >> 6;
    int row0 = blockIdx.y * 128, col0 = blockIdx.x * 128;
    int sr = t >> 1, shalf = t & 1;
    int wm = (wave >> 1) * 64, wn = (wave & 1) * 64;
    int fr = lane & 15, fq = lane >> 4;
    f32x4 acc[4][4];
    #pragma unroll
    for (int i = 0; i < 4; i++)
        #pragma unroll
        for (int j = 0; j < 4; j++)
            acc[i][j] = (f32x4){0.f, 0.f, 0.f, 0.f};

    for (int k0 = 0; k0 < K; k0 += 32) {
        #pragma unroll
        for (int j = 0; j < 2; j++) {
            int koff = (shalf + 2 * j) * 8;
            int grow = row0 + sr;
            uint4 av = make_uint4(0u, 0u, 0u, 0u);
            if (grow < M) av = *(const uint4*)(A + (size_t)grow * K + k0 + koff);
            *(uint4*)&As[sr][koff] = av;
            uint4 bv = *(const uint4*)(Bt + (size_t)(col0 + sr) * K + k0 + koff);
            *(uint4*)&Bs[sr][koff] = bv;
        }
        __syncthreads();
        bf16x8 af[4], bfr[4];
        #pragma unroll
        for (int mt = 0; mt < 4; mt++)
            af[mt] = *(const bf16x8*)&As[wm + mt * 16 + fr][fq * 8];
        #pragma unroll
        for (int nt = 0; nt < 4; nt++)
            bfr[nt] = *(const bf16x8*)&Bs[wn + nt * 16 + fr][fq * 8];
        #pragma unroll
        for (int mt = 0; mt < 4; mt++)
            #pragma unroll
            for (int nt = 0; nt < 4; nt++)
                acc[mt][nt] = __builtin_amdgcn_mfma_f32_16x16x32_bf16(
                    af[mt], bfr[nt], acc[mt][nt], 0, 0, 0);
        __syncthreads();
    }
    #pragma unroll
    for (int nt = 0; nt < 4; nt++) {
        int col = col0 + wn + nt * 16 + fr;
        float bv = bias[col];
        #pragma unroll
        for (int mt = 0; mt < 4; mt++) {
            #pragma unroll
            for (int gi = 0; gi < 4; gi++) {
                int row = row0 + wm + mt * 16 + fq * 4 + gi;
                if (row < M) {
                    float val = acc[mt][nt][gi] + bv;
                    if (epi == 1) val = gelu_f(val);
                    size_t off = (size_t)row * N + col;
                    if (epi == 2) ((float*)Cout)[off] = val + R[off];
                    else          ((ushort_t*)Cout)[off] = f2b(val);
                }
            }
        }
    }
}

// ---------- MFMA flash attention ----------
// grid (4 q-tiles, 384 bh), 4 waves, each wave = 16 q-rows.
// LDS: KbP = K rows [224][72] (reused as P [64][232] after barrier), Vt = V^T [64][232]
#define TPAD_ 224
#define KROW_ 72
#define VROW_ 232
__global__ __launch_bounds__(256) void attn_kernel(const ushort_t* qkv, ushort_t* O) {
    __shared__ ushort_t KbP[TPAD_ * KROW_];
    __shared__ ushort_t Vt[64 * VROW_];
    int qt = blockIdx.x;
    int bh = blockIdx.y;
    int bb = bh / 12, hh = bh % 12;
    int t = threadIdx.x, lane = t & 63, w = t >> 6;
    int q = lane >> 4, n = lane & 15;
    size_t base = (size_t)bb * 197 * 2304 + hh * 64;

    // stage K rows (row-major, zero-pad rows >=197)
    for (int e = t; e < TPAD_ * 8; e += 256) {
        int j = e >> 3, d8 = e & 7;
        uint4 kv = make_uint4(0u, 0u, 0u, 0u);
        if (j < 197) kv = *(const uint4*)(qkv + base + (size_t)j * 2304 + 768 + d8 * 8);
        *(uint4*)&KbP[j * KROW_ + d8 * 8] = kv;
    }
    // stage V transposed: Vt[d][j]
    for (int d8 = 0; d8 < 8; d8++) {
        int j = t;
        if (j < 197) {
            uint4 vv = *(const uint4*)(qkv + base + (size_t)j * 2304 + 1536 + d8 * 8);
            ushort_t tmp[8];
            *(uint4*)tmp = vv;
            #pragma unroll
            for (int i = 0; i < 8; i++) Vt[(d8 * 8 + i) * VROW_ + j] = tmp[i];
        }
    }
    // zero pad cols j=197..223 of Vt
    {
        int j = 197 + (t & 31);
        if (j < TPAD_)
            for (int d = t >> 5; d < 64; d += 8) Vt[d * VROW_ + j] = 0;
    }
    __syncthreads();

    // Q fragments for this wave's 16 rows (A layout: m=lane&15, k=quad*8+j)
    int i0 = qt * 64 + w * 16;
    bf16x8 qf[2];
    {
        int row = i0 + n;
        #pragma unroll
        for (int kc = 0; kc < 2; kc++) {
            uint4 qv = make_uint4(0u, 0u, 0u, 0u);
            if (row < 197)
                qv = *(const uint4*)(qkv + base + (size_t)row * 2304 + kc * 32 + q * 8);
            qf[kc] = *(bf16x8*)&qv;
        }
    }
    // S = Q K^T over 14 col tiles
    f32x4 sa[14];
    #pragma unroll
    for (int ct = 0; ct < 14; ct++) sa[ct] = (f32x4){0.f, 0.f, 0.f, 0.f};
    #pragma unroll
    for (int kc = 0; kc < 2; kc++) {
        #pragma unroll
        for (int ct = 0; ct < 14; ct++) {
            bf16x8 kf = *(const bf16x8*)&KbP[(ct * 16 + n) * KROW_ + kc * 32 + q * 8];
            sa[ct] = __builtin_amdgcn_mfma_f32_16x16x32_bf16(qf[kc], kf, sa[ct], 0, 0, 0);
        }
    }
    // softmax (rows r = q*4+gi spread over the 16 lanes n of this quad)
    float mx[4] = {-1e30f, -1e30f, -1e30f, -1e30f};
    #pragma unroll
    for (int ct = 0; ct < 14; ct++) {
        bool v = (ct * 16 + n) < 197;
        #pragma unroll
        for (int gi = 0; gi < 4; gi++) {
            float s = sa[ct][gi] * 0.125f;
            sa[ct][gi] = s;
            if (v) mx[gi] = fmaxf(mx[gi], s);
        }
    }
    #pragma unroll
    for (int msk = 1; msk < 16; msk <<= 1)
        #pragma unroll
        for (int gi = 0; gi < 4; gi++)
            mx[gi] = fmaxf(mx[gi], __shfl_xor(mx[gi], msk, 64));
    float sm[4] = {0.f, 0.f, 0.f, 0.f};
    #pragma unroll
    for (int ct = 0; ct < 14; ct++) {
        bool v = (ct * 16 + n) < 197;
        #pragma unroll
        for (int gi = 0; gi < 4; gi++) {
            float p = v ? __expf(sa[ct][gi] - mx[gi]) : 0.f;
            sa[ct][gi] = p;
            sm[gi] += p;
        }
    }
    #pragma unroll
    for (int msk = 1; msk < 16; msk <<= 1)
        #pragma unroll
        for (int gi = 0; gi < 4; gi++)
            sm[gi] += __shfl_xor(sm[gi], msk, 64);
    #pragma unroll
    for (int gi = 0; gi < 4; gi++) sm[gi] = 1.f / sm[gi];

    __syncthreads();   // all waves done reading K before P overwrites KbP

    // write P (C layout -> LDS rows), rows w*16 + q*4+gi
    #pragma unroll
    for (int ct = 0; ct < 14; ct++)
        #pragma unroll
        for (int gi = 0; gi < 4; gi++)
            KbP[(w * 16 + q * 4 + gi) * VROW_ + ct * 16 + n] = f2b(sa[ct][gi] * sm[gi]);

    // O = P V  (A = P rows m=lane&15, B = Vt rows n=out col)
    f32x4 oa[4];
    #pragma unroll
    for (int nt = 0; nt < 4; nt++) oa[nt] = (f32x4){0.f, 0.f, 0.f, 0.f};
    #pragma unroll
    for (int kc = 0; kc < 7; kc++) {
        bf16x8 pf = *(const bf16x8*)&KbP[(w * 16 + n) * VROW_ + kc * 32 + q * 8];
        #pragma unroll
        for (int nt = 0; nt < 4; nt++) {
            bf16x8 vf = *(const bf16x8*)&Vt[(nt * 16 + n) * VROW_ + kc * 32 + q * 8];
            oa[nt] = __builtin_amdgcn_mfma_f32_16x16x32_bf16(pf, vf, oa[nt], 0, 0, 0);
        }
    }
    #pragma unroll
    for (int nt = 0; nt < 4; nt++) {
        #pragma unroll
        for (int gi = 0; gi < 4; gi++) {
            int row = i0 + q * 4 + gi;
            if (row < 197)
                O[((size_t)bb * 197 + row) * 768 + hh * 64 + nt * 16 + n] = f2b(oa[nt][gi]);
        }
    }
}

extern "C" void kernel_launch(void* const* d_in, const int* in_sizes, int n_in,
                              void* d_out, int out_size, void* d_ws, size_t ws_size,
                              hipStream_t stream) {
    const float* img   = (const float*)d_in[0];
    const float* plg   = (const float*)d_in[1];
    const float* plb   = (const float*)d_in[2];
    const float* Wp    = (const float*)d_in[3];
    const float* bp    = (const float*)d_in[4];
    const float* elg   = (const float*)d_in[5];
    const float* elb   = (const float*)d_in[6];
    const float* pos   = (const float*)d_in[7];
    const float* cls   = (const float*)d_in[8];
    const float* l1g   = (const float*)d_in[9];
    const float* l1b   = (const float*)d_in[10];
    const float* Wqkv  = (const float*)d_in[11];
    const float* bqkv  = (const float*)d_in[12];
    const float* Wo    = (const float*)d_in[13];
    const float* bo    = (const float*)d_in[14];
    const float* l2g   = (const float*)d_in[15];
    const float* l2b   = (const float*)d_in[16];
    const float* W1    = (const float*)d_in[17];
    const float* b1    = (const float*)d_in[18];
    const float* W2    = (const float*)d_in[19];
    const float* b2    = (const float*)d_in[20];
    const float* ng    = (const float*)d_in[21];
    const float* nb    = (const float*)d_in[22];

    char* ws = (char*)d_ws;
    float*    x    = (float*)(ws + X_OFF);
    ushort_t* h    = (ushort_t*)(ws + H_OFF);
    ushort_t* qkvb = (ushort_t*)(ws + QKVB_OFF);
    ushort_t* o    = (ushort_t*)(ws + O_OFF);
    ushort_t* mid  = (ushort_t*)(ws + MID_OFF);
    ushort_t* wt   = (ushort_t*)(ws + WT_OFF);
    uint_t*   hist = (uint_t*)(ws + HIST_OFF);
    uint_t*   h2   = (uint_t*)(ws + H2_OFF);
    float*    sums = (float*)(ws + SUMS_OFF);
    uint_t*   sel  = (uint_t*)(ws + SEL_OFF);
    float*    par  = (float*)(ws + PAR_OFF);

    hipMemsetAsync(ws + HIST_OFF, 0, SEL_OFF - HIST_OFF, stream);

    hist1_kernel<<<dim3(64, NMAT_), 256, 0, stream>>>(Wqkv, Wo, W1, W2, hist, sums);
    sel1_kernel<<<NMAT_, 256, 0, stream>>>(hist, sel);
    hist2_kernel<<<dim3(64, NMAT_), 256, 0, stream>>>(Wqkv, Wo, W1, W2, sel, h2);
    sel2_kernel<<<NMAT_, 256, 0, stream>>>(h2, sel, sums, par);

    patchify_kernel<<<M0_, 256, 0, stream>>>(img, plg, plb, h);
    trq_kernel<<<dim3(768 / 32, 768 / 32), 256, 0, stream>>>(Wp, wt, 768, 768, par, -1);
    gemm_kernel<<<dim3(6, 49), 256, 0, stream>>>(h, wt, bp, o, nullptr, M0_, 768, 768, 0);
    assemble_kernel<<<M_, 256, 0, stream>>>(o, cls, pos, elg, elb, x);

    for (int i = 0; i < DEPTH_; i++) {
        ln_kernel<<<M_, 256, 0, stream>>>(x, h, nullptr, l1g + i * 768, l1b + i * 768);
        trq_kernel<<<dim3(2304 / 32, 768 / 32), 256, 0, stream>>>(
            Wqkv + (size_t)i * 1769472, wt, 768, 2304, par, i);
        gemm_kernel<<<dim3(18, 50), 256, 0, stream>>>(h, wt, bqkv + i * 2304, qkvb, nullptr,
                                                      M_, 2304, 768, 0);
        attn_kernel<<<dim3(4, B_ * 12), 256, 0, stream>>>(qkvb, o);
        trq_kernel<<<dim3(768 / 32, 768 / 32), 256, 0, stream>>>(
            Wo + (size_t)i * 589824, wt, 768, 768, par, 12 + i);
        gemm_kernel<<<dim3(6, 50), 256, 0, stream>>>(o, wt, bo + i * 768, x, x,
                                                     M_, 768, 768, 2);
        ln_kernel<<<M_, 256, 0, stream>>>(x, h, nullptr, l2g + i * 768, l2b + i * 768);
        trq_kernel<<<dim3(3072 / 32, 768 / 32), 256, 0, stream>>>(
            W1 + (size_t)i * 2359296, wt, 768, 3072, par, (i < 11) ? 24 + i : -1);
        gemm_kernel<<<dim3(24, 50), 256, 0, stream>>>(h, wt, b1 + i * 3072, mid, nullptr,
                                                      M_, 3072, 768, 1);
        trq_kernel<<<dim3(768 / 32, 3072 / 32), 256, 0, stream>>>(
            W2 + (size_t)i * 2359296, wt, 3072, 768, par, (i < 11) ? 35 + i : -1);
        gemm_kernel<<<dim3(6, 50), 256, 0, stream>>>(mid, wt, b2 + i * 768, x, x,
                                                     M_, 768, 3072, 2);
    }

    ln_kernel<<<M_, 256, 0, stream>>>(x, nullptr, (float*)d_out, ng, nb);
}